// Round 7
// baseline (190.100 us; speedup 1.0000x reference)
//
#include <hip/hip_runtime.h>
#include <stdint.h>

// QuantizedConv2d int8 implicit GEMM via MFMA i32_16x16x64_i8.
// N=32, C_in=128, H=W=56, C_out=256, 3x3, pad 1, stride 1.
// Output int8 values stored as int32 (harness reads integer outputs as np.int32).
//
// R17: block-level oversubscription replaces in-kernel pipelining.
// Budget audit of R13-R16: per CU, LDS reads 17.6 us + MFMA 15 us + VALU 8 us
// ~= the observed ~50 us -> at 2 waves/SIMD the pipes SERIALIZE per-wave;
// overlap needs more, desynchronized waves (m114). Persistent structures
// can't get there (the factor 7 in 1792 tiles never divides 4 blocks/CU;
// bigger slabs blow LDS). So: 1792 one-shot blocks, one 112M x 128co tile
// each, 32 KB LDS, ~100 VGPR -> 4-5 resident blocks/CU (16-20 waves/CU),
// dynamically backfilled. Staggered blocks overlap stage/compute/store in
// hardware; dynamic dispatch self-balances the 7 tiles/CU average. No
// barriers except the post-stage __syncthreads, no manual vmcnt.
// K-loop unchanged from R16: ratio-2 (4 MFMA per a0/a1 LDS pair), B streamed
// 2 taps ahead from L2 (laundered base blocks load clustering), setprio(1).

#define NB 32
#define CI 128
#define HH 56
#define WW 56
#define CO 256
#define SPA (HH * WW)              // 3136 = 28 slabs x 112 (2 image rows each)
#define HP 58
#define WP 64
#define XP2_BYTES (NB * HP * WP * CI)      // 15204352
#define BP_BYTES (9 * 2 * 4 * CO * 16)     // 294912
#define ABUF (4 * 8192)                    // 4 padded rows = 32 KB

typedef int v4i __attribute__((ext_vector_type(4)));

// ---- prep (unchanged from R10) ----
// [0,1792): pack one (n,h) row -> padded NHWC int8, pad byte = zp, XOR-swizzled
// [1792,1856): border h-rows = zp
// [1856,2112): weight pack + BG[co] = bias - zp*S9
__global__ __launch_bounds__(256) void prep_kernel(
    const int* __restrict__ x, const int* __restrict__ wgt,
    const int* __restrict__ bias, const int* __restrict__ zpi,
    int8_t* __restrict__ xp2, int8_t* __restrict__ bp, int* __restrict__ BG)
{
    __shared__ int sm[1824];
    const int tid = threadIdx.x, bid = blockIdx.x;
    const int zp = *zpi;
    const int zp4 = (zp & 255) * 0x01010101;

    if (bid < HH * NB) {
        const int n = bid / HH, h = bid % HH;
        #pragma unroll
        for (int it = 0; it < 7; ++it) {
            int j = tid + it * 256;                 // 1792 = 128 ci x 14 w4
            int ci = j / 14, w4 = j - ci * 14;
            const v4i v = *(const v4i*)(x + ((n * CI + ci) * HH + h) * WW + w4 * 4);
            sm[w4 * 130 + ci] = (v.x & 255) | ((v.y & 255) << 8) |
                                ((v.z & 255) << 16) | (v.w << 24);
        }
        __syncthreads();
        int* od = (int*)xp2 + (n * HP + h + 1) * (WP * CI / 4);  // 2048 dwords
        #pragma unroll
        for (int it = 0; it < 8; ++it) {
            int j = tid + it * 256;                 // j = widx*32 + ci4
            int widx = j >> 5, ci4 = j & 31;
            int val = zp4;                          // pad value = zp
            if (widx >= 1 && widx <= WW) {
                int w = widx - 1;
                int base = (w >> 2) * 130 + ci4 * 4;
                int sh = (w & 3) * 8;
                val = ((sm[base] >> sh) & 0xff) | (((sm[base+1] >> sh) & 0xff) << 8) |
                      (((sm[base+2] >> sh) & 0xff) << 16) | ((sm[base+3] >> sh) << 24);
            }
            od[j ^ ((widx & 7) << 2)] = val;        // XOR-swizzle 16-B units
        }
    } else if (bid < HH * NB + 2 * NB) {
        const int z = bid - HH * NB;
        const int n = z >> 1, hidx = (z & 1) ? (HP - 1) : 0;
        int* od = (int*)xp2 + (n * HP + hidx) * (WP * CI / 4);
        #pragma unroll
        for (int it = 0; it < 8; ++it) od[tid + it * 256] = zp4;  // zp border rows
    } else {
        const int co = bid - (HH * NB + 2 * NB);
        for (int j = tid; j < 1152; j += 256) sm[j] = wgt[co * 1152 + j];  // [ci][9]
        __syncthreads();
        for (int j = tid; j < 288; j += 256) {      // 9t x 2c64 x 4q x 4j4
            int j4 = j & 3, q = (j >> 2) & 3, c64 = (j >> 4) & 1, t = j >> 5;
            int ci = c64 * 64 + q * 16 + j4 * 4;
            int b0 = sm[(ci + 0) * 9 + t] & 255, b1 = sm[(ci + 1) * 9 + t] & 255;
            int b2 = sm[(ci + 2) * 9 + t] & 255, b3 = sm[(ci + 3) * 9 + t];
            ((int*)bp)[((t * 2 + c64) * 4 + q) * 1024 + co * 4 + j4] =
                b0 | (b1 << 8) | (b2 << 16) | (b3 << 24);
        }
        if (tid < 9) {
            int s = 0;
            for (int ci = 0; ci < CI; ++ci) s += sm[ci * 9 + tid];
            sm[1152 + tid] = s;
        }
        __syncthreads();
        if (tid == 0) {
            int s9 = 0;
            for (int t = 0; t < 9; ++t) s9 += sm[1152 + t];
            BG[co] = bias[co] - zp * s9;            // cls-independent correction
        }
    }
}

// ---- main: 1792 one-shot blocks x 256 thr; block = one 112M x 128co tile ----
// 32 KB LDS -> 4-5 resident blocks/CU, dynamically backfilled.
__global__ __launch_bounds__(256) void qconv_mfma(
    const int8_t* __restrict__ xp2, const int8_t* __restrict__ bp,
    const int* __restrict__ BG,
    const float* __restrict__ si, const float* __restrict__ sw,
    const float* __restrict__ so, const int* __restrict__ zpo,
    int* __restrict__ out)
{
    const int tid  = threadIdx.x, lane = tid & 63, wid = tid >> 6;
    const int quad = lane >> 4, lo16 = lane & 15;
    const int bid  = blockIdx.x;                    // 1792 blocks
    const int xcd  = bid & 7, idx = bid >> 3;       // idx 0..223 per XCD
    const int n    = xcd * 4 + (idx & 3);           // 4 n-images per XCD (L2)
    const int cb   = (idx >> 2) & 1;
    const int s2   = idx >> 3;                      // slab 0..27
    const int cw   = cb * 128 + wid * 32;           // wave co base (32 co)

    __shared__ __attribute__((aligned(16))) int8_t Asm[ABUF];  // 32 KB

    // ---- stage this tile's A slab (4 padded rows, 32 KB) ----
    const int8_t* src0 = xp2 + (((size_t)n * HP + 2 * s2) << 13);
    #pragma unroll
    for (int k = 0; k < 8; ++k) {
        const int u = wid + 4 * k;                  // 32 x 1-KB units
        __builtin_amdgcn_global_load_lds(
            (const __attribute__((address_space(1))) void*)(src0 + (u << 10) + lane * 16),
            (__attribute__((address_space(3))) void*)(&Asm[u << 10]), 16, 0, 0);
    }

    int bgv[2];
    #pragma unroll
    for (int ct = 0; ct < 2; ++ct) bgv[ct] = BG[cw + ct * 16 + lo16];
    const float rs = (*si) * (*sw) / (*so);
    const float zo = (float)(*zpo);

    // per-mt geometry (slab-local): base offset + packed swizzle per tap-col
    int boff[7], sw3[7];
    #pragma unroll
    for (int mt = 0; mt < 7; ++mt) {
        const int ml = mt * 16 + lo16;              // 0..111 within slab
        const int srow = ml / 56, scol = ml - srow * 56;
        boff[mt] = srow * 8192 + scol * 128 + quad * 16;
        int s0 = ((scol + 0) & 7) << 4, s1 = ((scol + 1) & 7) << 4,
            s2x = ((scol + 2) & 7) << 4;
        sw3[mt] = s0 | (s1 << 8) | (s2x << 16);     // swizzle per dc, packed
    }

    // B stream base for this wave: page (t*8 + c64*4 + quad), entry co*16
    const int8_t* bwav = bp + ((size_t)quad << 12) + ((cw + lo16) << 4);

    int* optr0 = out + ((size_t)n * CO + cw + lo16) * SPA + quad * 4;
    int* optr1 = optr0 + 16 * SPA;

    // issue B fragments for tap tp (laundered base: stops load clustering)
    #define BLOAD(tp) {                                                        \
        const int8_t* bb = bwav + ((tp) * 8 << 12);                            \
        asm volatile("" : "+v"(bb));                                           \
        bt[tp][0] = *(const v4i*)(bb);                                         \
        bt[tp][1] = *(const v4i*)(bb + 256);                                   \
        bt[tp][2] = *(const v4i*)(bb + 16384);                                 \
        bt[tp][3] = *(const v4i*)(bb + 16384 + 256);                           \
    }

    v4i bt[9][4];                                   // streamed B (short-lived)
    BLOAD(0); BLOAD(1);

    v4i acc[7][2];
    #pragma unroll
    for (int mt = 0; mt < 7; ++mt) {
        acc[mt][0] = (v4i){0, 0, 0, 0};
        acc[mt][1] = (v4i){0, 0, 0, 0};
    }

    __syncthreads();                                // A slab staged

    // ---- K-loop: 9 taps x 7 mt x (2 LDS reads + 4 MFMA); B 2 taps ahead ----
    __builtin_amdgcn_s_setprio(1);
    #pragma unroll
    for (int tp = 0; tp < 9; ++tp) {
        if (tp + 2 <= 8) BLOAD(tp + 2);
        const int dr = tp / 3, dc = tp % 3;
        #pragma unroll
        for (int mt = 0; mt < 7; ++mt) {
            const int off  = boff[mt] + dr * 8192 + dc * 128;
            const int phys = off ^ ((sw3[mt] >> (8 * dc)) & 0x70);
            v4i a0 = *(const v4i*)(Asm + phys);           // logical ci 0..63
            v4i a1 = *(const v4i*)(Asm + (phys ^ 64));    // logical +64 -> phys^64
            acc[mt][0] = __builtin_amdgcn_mfma_i32_16x16x64_i8(a0, bt[tp][0], acc[mt][0], 0, 0, 0);
            acc[mt][1] = __builtin_amdgcn_mfma_i32_16x16x64_i8(a0, bt[tp][1], acc[mt][1], 0, 0, 0);
            acc[mt][0] = __builtin_amdgcn_mfma_i32_16x16x64_i8(a1, bt[tp][2], acc[mt][0], 0, 0, 0);
            acc[mt][1] = __builtin_amdgcn_mfma_i32_16x16x64_i8(a1, bt[tp][3], acc[mt][1], 0, 0, 0);
        }
    }
    __builtin_amdgcn_s_setprio(0);
    #undef BLOAD

    // ---- epilogue: requant + 14 direct v4i stores; kernel ends ----
    const int m0 = s2 * 112;
    #pragma unroll
    for (int mt = 0; mt < 7; ++mt) {
        v4i v0, v1;
        #pragma unroll
        for (int i4 = 0; i4 < 4; ++i4) {            // C/D row = quad*4+i4
            float y0 = rintf((float)(acc[mt][0][i4] + bgv[0]) * rs + zo);
            float y1 = rintf((float)(acc[mt][1][i4] + bgv[1]) * rs + zo);
            v0[i4] = (int)fminf(fmaxf(y0, -128.f), 127.f);
            v1[i4] = (int)fminf(fmaxf(y1, -128.f), 127.f);
        }
        *(v4i*)(optr0 + m0 + mt * 16) = v0;
        *(v4i*)(optr1 + m0 + mt * 16) = v1;
    }
}

extern "C" void kernel_launch(void* const* d_in, const int* in_sizes, int n_in,
                              void* d_out, int out_size, void* d_ws, size_t ws_size,
                              hipStream_t stream) {
    const int*   x    = (const int*)d_in[0];
    const int*   wgt  = (const int*)d_in[1];
    const int*   bias = (const int*)d_in[2];
    const float* si   = (const float*)d_in[3];
    const float* sw   = (const float*)d_in[4];
    const float* so   = (const float*)d_in[5];
    const int*   zpi  = (const int*)d_in[6];
    const int*   zpo  = (const int*)d_in[7];
    int* out = (int*)d_out;

    int8_t* xp2 = (int8_t*)d_ws;
    int8_t* bp  = xp2 + XP2_BYTES;
    int*    bg  = (int*)(bp + BP_BYTES);

    prep_kernel<<<HH * NB + 2 * NB + CO, 256, 0, stream>>>(x, wgt, bias, zpi, xp2, bp, bg);
    qconv_mfma<<<1792, 256, 0, stream>>>(xp2, bp, bg, si, sw, so, zpo, out);
}

// Round 8
// 182.077 us; speedup vs baseline: 1.0441x; 1.0441x over previous
//
#include <hip/hip_runtime.h>
#include <stdint.h>

// QuantizedConv2d int8 implicit GEMM via MFMA i32_16x16x64_i8.
// N=32, C_in=128, H=W=56, C_out=256, 3x3, pad 1, stride 1.
// Output int8 values stored as int32 (harness reads integer outputs as np.int32).
//
// R18 = R17 with the two in-wave serializers removed:
//  1. NO s_setprio. R17's prio(1) spanned the whole ~5000-cy K-loop; with
//     one-shot blocks nearly all resident waves sat at prio 1, starving any
//     wave in stage/B-load/epilogue (prio 0) on the same SIMD -> co-resident
//     blocks executed near-serially (occupancy 25.7%, no overlap).
//  2. Depth-2 software pipeline on A reads. R17's VGPR=72 left ~0 prefetch
//     depth -> each mt-iter ate the full ~120-cy LDS latency in-chain.
//     Flat 63-iter K-loop, 3-slot rotating a-regs: issue (it+2)'s two
//     ds_read_b128 while MFMAing slot it (~164 cy cover > 120 cy latency).
//     All indices compile-time after full unroll.
// Unchanged from R17: 1792 one-shot blocks (one 112M x 128co tile each,
// 32 KB LDS, 4-5 resident/CU, dynamically backfilled), ratio-2 K-loop
// (4 MFMA per a0/a1 pair), B streamed 2 taps ahead from L2 via laundered
// base, single __syncthreads, direct v4i stores, XCD swizzle.

#define NB 32
#define CI 128
#define HH 56
#define WW 56
#define CO 256
#define SPA (HH * WW)              // 3136 = 28 slabs x 112 (2 image rows each)
#define HP 58
#define WP 64
#define XP2_BYTES (NB * HP * WP * CI)      // 15204352
#define BP_BYTES (9 * 2 * 4 * CO * 16)     // 294912
#define ABUF (4 * 8192)                    // 4 padded rows = 32 KB

typedef int v4i __attribute__((ext_vector_type(4)));

// ---- prep (unchanged from R10) ----
// [0,1792): pack one (n,h) row -> padded NHWC int8, pad byte = zp, XOR-swizzled
// [1792,1856): border h-rows = zp
// [1856,2112): weight pack + BG[co] = bias - zp*S9
__global__ __launch_bounds__(256) void prep_kernel(
    const int* __restrict__ x, const int* __restrict__ wgt,
    const int* __restrict__ bias, const int* __restrict__ zpi,
    int8_t* __restrict__ xp2, int8_t* __restrict__ bp, int* __restrict__ BG)
{
    __shared__ int sm[1824];
    const int tid = threadIdx.x, bid = blockIdx.x;
    const int zp = *zpi;
    const int zp4 = (zp & 255) * 0x01010101;

    if (bid < HH * NB) {
        const int n = bid / HH, h = bid % HH;
        #pragma unroll
        for (int it = 0; it < 7; ++it) {
            int j = tid + it * 256;                 // 1792 = 128 ci x 14 w4
            int ci = j / 14, w4 = j - ci * 14;
            const v4i v = *(const v4i*)(x + ((n * CI + ci) * HH + h) * WW + w4 * 4);
            sm[w4 * 130 + ci] = (v.x & 255) | ((v.y & 255) << 8) |
                                ((v.z & 255) << 16) | (v.w << 24);
        }
        __syncthreads();
        int* od = (int*)xp2 + (n * HP + h + 1) * (WP * CI / 4);  // 2048 dwords
        #pragma unroll
        for (int it = 0; it < 8; ++it) {
            int j = tid + it * 256;                 // j = widx*32 + ci4
            int widx = j >> 5, ci4 = j & 31;
            int val = zp4;                          // pad value = zp
            if (widx >= 1 && widx <= WW) {
                int w = widx - 1;
                int base = (w >> 2) * 130 + ci4 * 4;
                int sh = (w & 3) * 8;
                val = ((sm[base] >> sh) & 0xff) | (((sm[base+1] >> sh) & 0xff) << 8) |
                      (((sm[base+2] >> sh) & 0xff) << 16) | ((sm[base+3] >> sh) << 24);
            }
            od[j ^ ((widx & 7) << 2)] = val;        // XOR-swizzle 16-B units
        }
    } else if (bid < HH * NB + 2 * NB) {
        const int z = bid - HH * NB;
        const int n = z >> 1, hidx = (z & 1) ? (HP - 1) : 0;
        int* od = (int*)xp2 + (n * HP + hidx) * (WP * CI / 4);
        #pragma unroll
        for (int it = 0; it < 8; ++it) od[tid + it * 256] = zp4;  // zp border rows
    } else {
        const int co = bid - (HH * NB + 2 * NB);
        for (int j = tid; j < 1152; j += 256) sm[j] = wgt[co * 1152 + j];  // [ci][9]
        __syncthreads();
        for (int j = tid; j < 288; j += 256) {      // 9t x 2c64 x 4q x 4j4
            int j4 = j & 3, q = (j >> 2) & 3, c64 = (j >> 4) & 1, t = j >> 5;
            int ci = c64 * 64 + q * 16 + j4 * 4;
            int b0 = sm[(ci + 0) * 9 + t] & 255, b1 = sm[(ci + 1) * 9 + t] & 255;
            int b2 = sm[(ci + 2) * 9 + t] & 255, b3 = sm[(ci + 3) * 9 + t];
            ((int*)bp)[((t * 2 + c64) * 4 + q) * 1024 + co * 4 + j4] =
                b0 | (b1 << 8) | (b2 << 16) | (b3 << 24);
        }
        if (tid < 9) {
            int s = 0;
            for (int ci = 0; ci < CI; ++ci) s += sm[ci * 9 + tid];
            sm[1152 + tid] = s;
        }
        __syncthreads();
        if (tid == 0) {
            int s9 = 0;
            for (int t = 0; t < 9; ++t) s9 += sm[1152 + t];
            BG[co] = bias[co] - zp * s9;            // cls-independent correction
        }
    }
}

// ---- main: 1792 one-shot blocks x 256 thr; block = one 112M x 128co tile ----
__global__ __launch_bounds__(256) void qconv_mfma(
    const int8_t* __restrict__ xp2, const int8_t* __restrict__ bp,
    const int* __restrict__ BG,
    const float* __restrict__ si, const float* __restrict__ sw,
    const float* __restrict__ so, const int* __restrict__ zpo,
    int* __restrict__ out)
{
    const int tid  = threadIdx.x, lane = tid & 63, wid = tid >> 6;
    const int quad = lane >> 4, lo16 = lane & 15;
    const int bid  = blockIdx.x;                    // 1792 blocks
    const int xcd  = bid & 7, idx = bid >> 3;       // idx 0..223 per XCD
    const int n    = xcd * 4 + (idx & 3);           // 4 n-images per XCD (L2)
    const int cb   = (idx >> 2) & 1;
    const int s2   = idx >> 3;                      // slab 0..27
    const int cw   = cb * 128 + wid * 32;           // wave co base (32 co)

    __shared__ __attribute__((aligned(16))) int8_t Asm[ABUF];  // 32 KB

    // ---- stage this tile's A slab (4 padded rows, 32 KB) ----
    const int8_t* src0 = xp2 + (((size_t)n * HP + 2 * s2) << 13);
    #pragma unroll
    for (int k = 0; k < 8; ++k) {
        const int u = wid + 4 * k;                  // 32 x 1-KB units
        __builtin_amdgcn_global_load_lds(
            (const __attribute__((address_space(1))) void*)(src0 + (u << 10) + lane * 16),
            (__attribute__((address_space(3))) void*)(&Asm[u << 10]), 16, 0, 0);
    }

    int bgv[2];
    #pragma unroll
    for (int ct = 0; ct < 2; ++ct) bgv[ct] = BG[cw + ct * 16 + lo16];
    const float rs = (*si) * (*sw) / (*so);
    const float zo = (float)(*zpo);

    // per-mt geometry (slab-local): base offset + packed swizzle per tap-col
    int boff[7], sw3[7];
    #pragma unroll
    for (int mt = 0; mt < 7; ++mt) {
        const int ml = mt * 16 + lo16;              // 0..111 within slab
        const int srow = ml / 56, scol = ml - srow * 56;
        boff[mt] = srow * 8192 + scol * 128 + quad * 16;
        int t0 = ((scol + 0) & 7) << 4, t1 = ((scol + 1) & 7) << 4,
            t2 = ((scol + 2) & 7) << 4;
        sw3[mt] = t0 | (t1 << 8) | (t2 << 16);      // swizzle per dc, packed
    }

    // B stream base for this wave: page (t*8 + c64*4 + quad), entry co*16
    const int8_t* bwav = bp + ((size_t)quad << 12) + ((cw + lo16) << 4);

    int* optr0 = out + ((size_t)n * CO + cw + lo16) * SPA + quad * 4;
    int* optr1 = optr0 + 16 * SPA;

    // issue B fragments for tap tp (laundered base: stops load clustering)
    #define BLOAD(tp) {                                                        \
        const int8_t* bb = bwav + ((tp) * 8 << 12);                            \
        asm volatile("" : "+v"(bb));                                           \
        bt[tp][0] = *(const v4i*)(bb);                                         \
        bt[tp][1] = *(const v4i*)(bb + 256);                                   \
        bt[tp][2] = *(const v4i*)(bb + 16384);                                 \
        bt[tp][3] = *(const v4i*)(bb + 16384 + 256);                           \
    }

    // swizzled LDS address for (tp, mt)
    #define AADDR(tp, mt) \
        ((boff[mt] + ((tp) / 3) * 8192 + ((tp) % 3) * 128) ^ \
         ((sw3[mt] >> (8 * ((tp) % 3))) & 0x70))

    v4i bt[9][4];                                   // streamed B (short-lived)
    BLOAD(0); BLOAD(1);

    v4i acc[7][2];
    #pragma unroll
    for (int mt = 0; mt < 7; ++mt) {
        acc[mt][0] = (v4i){0, 0, 0, 0};
        acc[mt][1] = (v4i){0, 0, 0, 0};
    }

    __syncthreads();                                // A slab staged

    // ---- K-loop: flat 63 iters (tp = it/7, mt = it%7), depth-2 A pipeline.
    //      3-slot rotating regs; (it+2)'s 2 ds_reads issue under it's 4 MFMAs.
    v4i a0p[3], a1p[3];
    { const int p = AADDR(0, 0);
      a0p[0] = *(const v4i*)(Asm + p); a1p[0] = *(const v4i*)(Asm + (p ^ 64)); }
    { const int p = AADDR(0, 1);
      a0p[1] = *(const v4i*)(Asm + p); a1p[1] = *(const v4i*)(Asm + (p ^ 64)); }

    #pragma unroll
    for (int it = 0; it < 63; ++it) {
        const int tp = it / 7, mt = it % 7;
        if (mt == 0 && tp + 2 <= 8) BLOAD(tp + 2);  // B two taps ahead
        if (it + 2 < 63) {                          // A two iters ahead
            const int tp2 = (it + 2) / 7, mt2 = (it + 2) % 7;
            const int p = AADDR(tp2, mt2);
            a0p[(it + 2) % 3] = *(const v4i*)(Asm + p);
            a1p[(it + 2) % 3] = *(const v4i*)(Asm + (p ^ 64));
        }
        const v4i a0 = a0p[it % 3], a1 = a1p[it % 3];
        acc[mt][0] = __builtin_amdgcn_mfma_i32_16x16x64_i8(a0, bt[tp][0], acc[mt][0], 0, 0, 0);
        acc[mt][1] = __builtin_amdgcn_mfma_i32_16x16x64_i8(a0, bt[tp][1], acc[mt][1], 0, 0, 0);
        acc[mt][0] = __builtin_amdgcn_mfma_i32_16x16x64_i8(a1, bt[tp][2], acc[mt][0], 0, 0, 0);
        acc[mt][1] = __builtin_amdgcn_mfma_i32_16x16x64_i8(a1, bt[tp][3], acc[mt][1], 0, 0, 0);
    }
    #undef BLOAD
    #undef AADDR

    // ---- epilogue: requant + 14 direct v4i stores; kernel ends ----
    const int m0 = s2 * 112;
    #pragma unroll
    for (int mt = 0; mt < 7; ++mt) {
        v4i v0, v1;
        #pragma unroll
        for (int i4 = 0; i4 < 4; ++i4) {            // C/D row = quad*4+i4
            float y0 = rintf((float)(acc[mt][0][i4] + bgv[0]) * rs + zo);
            float y1 = rintf((float)(acc[mt][1][i4] + bgv[1]) * rs + zo);
            v0[i4] = (int)fminf(fmaxf(y0, -128.f), 127.f);
            v1[i4] = (int)fminf(fmaxf(y1, -128.f), 127.f);
        }
        *(v4i*)(optr0 + m0 + mt * 16) = v0;
        *(v4i*)(optr1 + m0 + mt * 16) = v1;
    }
}

extern "C" void kernel_launch(void* const* d_in, const int* in_sizes, int n_in,
                              void* d_out, int out_size, void* d_ws, size_t ws_size,
                              hipStream_t stream) {
    const int*   x    = (const int*)d_in[0];
    const int*   wgt  = (const int*)d_in[1];
    const int*   bias = (const int*)d_in[2];
    const float* si   = (const float*)d_in[3];
    const float* sw   = (const float*)d_in[4];
    const float* so   = (const float*)d_in[5];
    const int*   zpi  = (const int*)d_in[6];
    const int*   zpo  = (const int*)d_in[7];
    int* out = (int*)d_out;

    int8_t* xp2 = (int8_t*)d_ws;
    int8_t* bp  = xp2 + XP2_BYTES;
    int*    bg  = (int*)(bp + BP_BYTES);

    prep_kernel<<<HH * NB + 2 * NB + CO, 256, 0, stream>>>(x, wgt, bias, zpi, xp2, bp, bg);
    qconv_mfma<<<1792, 256, 0, stream>>>(xp2, bp, bg, si, sw, so, zpo, out);
}